// Round 10
// baseline (398.752 us; speedup 1.0000x reference)
//
#include <hip/hip_runtime.h>

#define EPS 1e-5f
#define WAVES 4

typedef __attribute__((ext_vector_type(8)))  short short8;
typedef __attribute__((ext_vector_type(16))) float f32x16;
typedef __attribute__((ext_vector_type(2)))  float f32x2;

__device__ inline unsigned f2bf(float f) {
    unsigned u = __builtin_bit_cast(unsigned, f);
    return (u + 0x7fffu + ((u >> 16) & 1u)) >> 16;   // RNE f32->bf16
}

// prep (unchanged from R7): two regions of d_ws
//  [0)      w2f:  bf16 w2 in mfma_f32_32x32x16_bf16 B-frag order
//           w2f[nf*8192 + ks*512 + lane*8 + e] = bf16(w2[ks*16+(lane>>5)*8+e][nf*32+(lane&31)])
//  [131072) embp: (emb + b2) as bf16 pairs
__global__ void prep(const float* __restrict__ w2, const float* __restrict__ emb,
                     const float* __restrict__ b2,
                     unsigned short* __restrict__ w2f, unsigned* __restrict__ embp) {
    int idx = blockIdx.x * 256 + threadIdx.x;
    if (idx < 65536) {
        int e    = idx & 7;
        int lane = (idx >> 3) & 63;
        int ks   = (idx >> 9) & 15;
        int nf   = idx >> 13;
        int k    = ks * 16 + ((lane >> 5) << 3) + e;
        int n    = nf * 32 + (lane & 31);
        w2f[idx] = (unsigned short)f2bf(w2[k * 256 + n]);
    } else if (idx < 65536 + 12800) {
        int i   = idx - 65536;
        int row = i >> 7;
        int w   = i & 127;
        int g   = w >> 5;
        int c   = w & 31;
        int clo = g * 64 + c;
        int chi = clo + 32;
        unsigned lo = f2bf(emb[row * 256 + clo] + b2[clo]);
        unsigned hi = f2bf(emb[row * 256 + chi] + b2[chi]);
        embp[i] = lo | (hi << 16);
    }
}

__global__ __launch_bounds__(256, 2) void fused_kernel(
    const int* __restrict__ z, const float* __restrict__ x,
    const float* __restrict__ w1, const float* __restrict__ b1,
    const unsigned short* __restrict__ w2f, const unsigned* __restrict__ embp,
    const float* __restrict__ gamma, const float* __restrict__ beta,
    float* __restrict__ out, int N)
{
    // All LDS PER-WAVE, zero barriers (within-wave producer/consumer; DS pipe is
    // in-order per wave). A-tile processed in TWO k-half passes over an 8KB
    // buffer -> block LDS 35KB -> up to 4 blocks/CU (vs 2 at 68KB). Same total
    // silu/B/MFMA work as the 16KB single-pass version.
    __shared__ char  p_lds[WAVES * 8192];    // per-wave [32][128] bf16, swizzled
    __shared__ float x_lds[WAVES][32][4];
    __shared__ int   z_lds[WAVES][32];

    const int tid  = threadIdx.x;
    const int wave = tid >> 6;
    const int lane = tid & 63;
    const int l31  = lane & 31;
    const int h    = lane >> 5;
    char* pbuf = p_lds + wave * 8192;

    const int tiles = N >> 5;
    const int t = blockIdx.x * WAVES + wave;
    if (t >= tiles) return;                  // per-wave exit legal: no barriers
    const int R = t << 5;

    if (lane < 32) {
        int r = R + lane;
        x_lds[wave][lane][0] = x[r * 3 + 0];
        x_lds[wave][lane][1] = x[r * 3 + 1];
        x_lds[wave][lane][2] = x[r * 3 + 2];
        z_lds[wave][lane]    = z[r];
    }

    // ---- init acc with packed-bf16 (emb+b2) gather (C/D layout): 64 u32 loads
    // fly while the first silu half executes.
    f32x16 acc[8];
#pragma unroll
    for (int j = 0; j < 16; ++j) {
        const int rl = (j & 3) + ((j >> 2) << 3) + (h << 2);
        const unsigned* er = embp + z_lds[wave][rl] * 128 + l31;
#pragma unroll
        for (int g = 0; g < 4; ++g) {
            unsigned u = er[g * 32];
            acc[2 * g][j]     = __builtin_bit_cast(float, u << 16);
            acc[2 * g + 1][j] = __builtin_bit_cast(float, u & 0xffff0000u);
        }
    }

    // ---- two k-half passes: silu [32][128] -> MFMA 8 ks, reuse the 8KB buffer
#pragma unroll
    for (int half = 0; half < 2; ++half) {
        // this lane computes p columns {c, c+1} of this half for all 32 rows
        const int c = half * 128 + lane * 2;
        const f32x2 wa = *(const f32x2*)(w1 + c);
        const f32x2 wb = *(const f32x2*)(w1 + 256 + c);
        const f32x2 wc = *(const f32x2*)(w1 + 512 + c);
        const f32x2 bb = *(const f32x2*)(b1 + c);
#pragma unroll
        for (int r = 0; r < 32; ++r) {
            float x0 = x_lds[wave][r][0];
            float x1 = x_lds[wave][r][1];
            float x2 = x_lds[wave][r][2];
            float t0 = x0 * wa[0] + x1 * wb[0] + x2 * wc[0] + bb[0];
            float t1 = x0 * wa[1] + x1 * wb[1] + x2 * wc[1] + bb[1];
            float s0 = t0 * __builtin_amdgcn_rcpf(1.f + __expf(-t0));
            float s1 = t1 * __builtin_amdgcn_rcpf(1.f + __expf(-t1));
            unsigned pv = f2bf(s0) | (f2bf(s1) << 16);
            int off = (r * 256 + lane * 4) ^ ((r & 7) << 4);
            *(unsigned*)(pbuf + off) = pv;
        }
        // MFMA: A-frag row=l31, k_local = ks*16 + h*8 (8 consecutive bf16)
#pragma unroll
        for (int ks = 0; ks < 8; ++ks) {
            int aoff = (l31 * 256 + ks * 32 + h * 16) ^ ((l31 & 7) << 4);
            short8 a = *(const short8*)(pbuf + aoff);
            const unsigned short* bp = w2f + (half * 8 + ks) * 512 + lane * 8;
#pragma unroll
            for (int nf = 0; nf < 8; ++nf) {
                short8 b = *(const short8*)(bp + nf * 8192);
                acc[nf] = __builtin_amdgcn_mfma_f32_32x32x16_bf16(a, b, acc[nf], 0, 0, 0);
            }
        }
    }

    // ---- epilogue: LayerNorm (row in one lane-half) ; direct NT stores
    // (bypass L2 write-allocate RFO). gamma/beta loaded here, not hoisted.
    float gv[8], bv[8];
#pragma unroll
    for (int nf = 0; nf < 8; ++nf) {
        int cc = nf * 32 + l31;
        gv[nf] = gamma[cc]; bv[nf] = beta[cc];
    }
#pragma unroll
    for (int j = 0; j < 16; ++j) {
        const int rl = (j & 3) + ((j >> 2) << 3) + (h << 2);
        float hv[8];
        float hsum = 0.f, hsq = 0.f;
#pragma unroll
        for (int nf = 0; nf < 8; ++nf) {
            float v = acc[nf][j];
            hv[nf] = v; hsum += v; hsq += v * v;
        }
#pragma unroll
        for (int d = 1; d < 32; d <<= 1) {
            hsum += __shfl_xor(hsum, d, 64);
            hsq  += __shfl_xor(hsq,  d, 64);
        }
        float mu  = hsum * (1.f / 256.f);
        float var = hsq * (1.f / 256.f) - mu * mu;
        float rs  = rsqrtf(var + EPS);
        float* orow = out + (size_t)(R + rl) * 256 + l31;
#pragma unroll
        for (int nf = 0; nf < 8; ++nf)
            __builtin_nontemporal_store((hv[nf] - mu) * rs * gv[nf] + bv[nf],
                                        orow + nf * 32);
    }
}

extern "C" void kernel_launch(void* const* d_in, const int* in_sizes, int n_in,
                              void* d_out, int out_size, void* d_ws, size_t ws_size,
                              hipStream_t stream) {
    const int*   z     = (const int*)d_in[0];
    const float* x     = (const float*)d_in[1];
    const float* emb   = (const float*)d_in[2];
    const float* w1    = (const float*)d_in[3];
    const float* b1    = (const float*)d_in[4];
    const float* w2    = (const float*)d_in[5];
    const float* b2    = (const float*)d_in[6];
    const float* gamma = (const float*)d_in[7];
    const float* beta  = (const float*)d_in[8];
    float* out = (float*)d_out;
    const int N = in_sizes[0];

    unsigned short* w2f  = (unsigned short*)d_ws;              // 128 KB
    unsigned*       embp = (unsigned*)((char*)d_ws + 131072);  // 50 KB bf16-pair emb+b2

    prep<<<(65536 + 12800 + 255) / 256, 256, 0, stream>>>(w2, emb, b2, w2f, embp);

    int tiles  = N >> 5;
    int blocks = (tiles + WAVES - 1) / WAVES;  // one 32-row tile per wave, one-shot
    fused_kernel<<<blocks, 256, 0, stream>>>(z, x, w1, b1, w2f, embp,
                                             gamma, beta, out, N);
}